// Round 17
// baseline (90.016 us; speedup 1.0000x reference)
//
#include <hip/hip_runtime.h>
#include <math.h>

// Planar normalizing flow, B=524288 rows, D=64, F=32 -- MFMA formulation v6.
//   Phase A (MFMA): S[32f x 64b] = W . X_tile^T, S quads written as ONE
//                   ds_write_b128 each (quad-XOR-swizzled layout)
//   Phase B (VALU): batch-read S (8 x ds_read_b128, one wait) -> recurrence
//                   runs ENTIRELY in registers (st[] overlay: element f is
//                   S+bs until step f, h[f] after; G zero-pad makes the
//                   mixed partial quad exact)
//   Phase C (MFMA): Z^T-tiles via swapped operands -> f4 epilogue
// vs r14/r16 (81/86us, all pipes <25%, latency-bound): the two structural
// stalls addressed are 4-wave block retirement (slowest-wave hostage;
// now 64-thread blocks, grid=ntiles, 16 slots/CU) and per-step LDS
// round-trips in the serial recurrence (32 x ds_read_b32 with conservative
// lgkmcnt; now zero LDS ops inside the chain).

#define NF_D 64
#define NF_F 32

typedef float f4 __attribute__((ext_vector_type(4)));
typedef float f32x4v __attribute__((ext_vector_type(4)));
typedef unsigned int u32;
typedef u32 u32x4 __attribute__((ext_vector_type(4)));
typedef short bf16x8 __attribute__((ext_vector_type(8)));

// wsbuf layout in 4-byte units:
#define WS_WF   0       // u32[8][64][4]  W A-frags, lin=(Mt*2+Kt)*2+p
#define WS_UF   2048    // u32[4][64][4]  Uhat frags (lane&15=d, k=f)
#define WS_GT   3072    // float[32][32]  G[f][g]=u_hat_g.w_f (g<f else 0)
#define WS_WUH  4096    // float[32]      w_f.uhat_f
#define WS_TOT  4128

__device__ __forceinline__ u32 fbits(float x){ union{float f;u32 u;} c; c.f=x; return c.u; }
__device__ __forceinline__ float asf(u32 u){ union{u32 u;float f;} c; c.u=u; return c.f; }
__device__ __forceinline__ u32 bfrnd(float x){ u32 b=fbits(x); return (b + 0x7FFFu + ((b>>16)&1u)) >> 16; }
__device__ __forceinline__ bf16x8 asbf(u32x4 v){ union{u32x4 u; bf16x8 b;} c; c.u=v; return c.b; }

// --- precompute: uhat, wuh, G, W/U fragment buffers ----------------------
__global__ void nf_precompute(const float* __restrict__ us,
                              const float* __restrict__ ws,
                              u32* __restrict__ wsb) {
  __shared__ float s_u[NF_F][NF_D];
  float* wsf = (float*)wsb;
  int t = threadIdx.x;
  if (t < NF_F) {
    const float* u = us + t * NF_D;
    const float* w = ws + t * NF_D;
    float wu = 0.f, n2 = 0.f;
    for (int d = 0; d < NF_D; ++d) {
      wu = fmaf(u[d], w[d], wu);
      n2 = fmaf(w[d], w[d], n2);
    }
    float sp = fmaxf(wu, 0.f) + log1pf(expf(-fabsf(wu)));  // softplus
    float coef = (sp - 1.f - wu) / sqrtf(n2);
    for (int d = 0; d < NF_D; ++d)
      s_u[t][d] = fmaf(coef, w[d], u[d]);                  // uhat
    wsf[WS_WUH + t] = fmaf(coef, n2, wu);                  // w_t.uhat_t
  }
  __syncthreads();
  // W A-frags: lane l holds W[fm=16Mt+(l&15)][k=32Kt+8*(l>>4)+j], j=0..7
  // p=0: bf16-trunc(hi); p=1: bf16-trunc(w - hi)
  for (int idx = t; idx < 8 * 64; idx += 256) {
    int lin = idx >> 6, l = idx & 63;
    int Mt = lin >> 2, Kt = (lin >> 1) & 1, p = lin & 1;
    int fm = 16 * Mt + (l & 15);
    int kb = 32 * Kt + 8 * (l >> 4);
    for (int i = 0; i < 4; ++i) {
      u32 pr[2];
      for (int e = 0; e < 2; ++e) {
        float w = ws[fm * NF_D + kb + 2 * i + e];
        u32 hb = fbits(w) & 0xFFFF0000u;
        pr[e] = (p == 0) ? (hb >> 16) : (fbits(w - asf(hb)) >> 16);
      }
      wsb[WS_WF + (lin * 64 + l) * 4 + i] = pr[0] | (pr[1] << 16);
    }
  }
  // U frags: lane l holds Uhat[f=8*(l>>4)+j][d=16Nt+(l&15)], rounded bf16
  for (int idx = t; idx < 4 * 64; idx += 256) {
    int l = idx & 63;
    int d = 16 * (idx >> 6) + (l & 15);
    int fb = 8 * (l >> 4);
    for (int i = 0; i < 4; ++i) {
      u32 r0 = bfrnd(s_u[fb + 2 * i][d]);
      u32 r1 = bfrnd(s_u[fb + 2 * i + 1][d]);
      wsb[WS_UF + idx * 4 + i] = r0 | (r1 << 16);
    }
  }
  // G[f][g] = u_hat_g . w_f for g<f, else 0
  for (int i = t; i < NF_F * NF_F; i += 256) {
    int f = i >> 5, g = i & 31;
    float s = 0.f;
    if (g < f) {
      const float* w = ws + f * NF_D;
      for (int d = 0; d < NF_D; ++d) s = fmaf(s_u[g][d], w[d], s);
    }
    wsf[WS_GT + i] = s;
  }
}

// tanh(x) = 1 - 2/(e^{2x}+1); hardware exp2/rcp; saturates to +-1.
__device__ __forceinline__ float fast_tanh(float x) {
  float e = __builtin_amdgcn_exp2f(x * 2.885390081777927f); // 2*log2(e)
  return 1.f - 2.f * __builtin_amdgcn_rcpf(e + 1.f);
}

#define MFMA __builtin_amdgcn_mfma_f32_16x16x32_bf16

// --- main: one 64-row tile per 64-thread block (1 wave) ------------------
__global__ __launch_bounds__(64) void nf_main(
    const float* __restrict__ x,
    const float* __restrict__ bs,
    const u32* __restrict__ wsb,
    float* __restrict__ out_z,
    float* __restrict__ out_ld,
    int B) {
  // Wave-private scratch (block = 1 wave): S[b][f] stored at
  // Sw[b*32 + 4*(q ^ (b&7)) + e] (q=f>>2, e=f&3): quad-granular XOR
  // swizzle keeps f4 alignment for b128 ops. Words [0,1024) reused for
  // packed-h after all S reads (same-wave program order).
  __shared__ float Sw[2048];
  const float* wsf = (const float*)wsb;

  int l = threadIdx.x;
  int tile = blockIdx.x;
  float* Sp = Sw;

  // persistent param fragments (once per wave)
  bf16x8 Wf[2][2][2], Uf[4];
  #pragma unroll
  for (int q = 0; q < 8; ++q)
    Wf[q >> 2][(q >> 1) & 1][q & 1] =
        asbf(*(const u32x4*)(wsb + WS_WF + (q * 64 + l) * 4));
  #pragma unroll
  for (int Nt = 0; Nt < 4; ++Nt)
    Uf[Nt] = asbf(*(const u32x4*)(wsb + WS_UF + (Nt * 64 + l) * 4));

  const float* xt = x + (size_t)tile * 64 * NF_D;

  // ---- Phase A: S = W . X^T (split bf16, 3 passes) ----------------------
  #pragma unroll
  for (int Nt = 0; Nt < 4; ++Nt) {
    bf16x8 Xh[2], Xl[2];
    #pragma unroll
    for (int Kt = 0; Kt < 2; ++Kt) {
      const f4* xp = (const f4*)(xt + ((l & 15) + 16 * Nt) * NF_D +
                                 32 * Kt + 8 * (l >> 4));
      f4 xa = xp[0], xb = xp[1];
      float xs[8] = {xa.x, xa.y, xa.z, xa.w, xb.x, xb.y, xb.z, xb.w};
      u32x4 hw, lw;
      #pragma unroll
      for (int i = 0; i < 4; ++i) {
        u32 b0 = fbits(xs[2 * i]), b1 = fbits(xs[2 * i + 1]);
        u32 h0 = b0 & 0xFFFF0000u, h1 = b1 & 0xFFFF0000u;
        hw[i] = (h0 >> 16) | h1;
        lw[i] = (fbits(xs[2 * i] - asf(h0)) >> 16) |
                (fbits(xs[2 * i + 1] - asf(h1)) & 0xFFFF0000u);
      }
      Xh[Kt] = asbf(hw);
      Xl[Kt] = asbf(lw);
    }
    #pragma unroll
    for (int Mt = 0; Mt < 2; ++Mt) {
      f32x4v a = {0.f, 0.f, 0.f, 0.f};
      #pragma unroll
      for (int Kt = 0; Kt < 2; ++Kt) {
        a = MFMA(Wf[Mt][Kt][0], Xh[Kt], a, 0, 0, 0);
        a = MFMA(Wf[Mt][Kt][0], Xl[Kt], a, 0, 0, 0);
        a = MFMA(Wf[Mt][Kt][1], Xh[Kt], a, 0, 0, 0);
      }
      // one b128 write per C/D quad: b=(l&15)+16Nt, quad qw=4Mt+(l>>4)
      int b = (l & 15) + 16 * Nt;
      int qw = 4 * Mt + (l >> 4);
      f4 av = {a[0], a[1], a[2], a[3]};
      *(f4*)(Sp + b * 32 + 4 * (qw ^ (b & 7))) = av;
    }
  }

  // ---- Phase B: in-register recurrence (lane = row b) -------------------
  // Batch-read all 8 S quads (one wait), add bs; st overlay: element f
  // holds S+bs until step f, h[f] after. G zero-pad (g>=f) makes every
  // partial-quad dot exact. Zero LDS ops inside the serial chain.
  const float* gt = wsf + WS_GT;
  const float* wuhp = wsf + WS_WUH;
  const f4* bs4 = (const f4*)bs;
  f4 st[8];
  #pragma unroll
  for (int q = 0; q < 8; ++q)
    st[q] = *(const f4*)(Sp + l * 32 + 4 * (q ^ (l & 7))) + bs4[q];

  float ldp = 1.f;
  #pragma unroll
  for (int f = 0; f < NF_F; ++f) {
    const f4* g4 = (const f4*)(gt + f * 32);
    f4 a = (f4)(0.f);
    #pragma unroll
    for (int q = 0; q < (f + 3) / 4; ++q)
      a += g4[q] * st[q];                // h for g<f; G zeros kill the rest
    float s = st[f >> 2][f & 3] + ((a.x + a.y) + (a.z + a.w));
    float hf = fast_tanh(s);
    ldp *= fmaf(fmaf(-hf, hf, 1.f), wuhp[f], 1.f);
    st[f >> 2][f & 3] = hf;              // overlay: h replaces S+bs
  }
  // pack h -> bf16 pairs into words [0,1024): Hw[i][b], b = lane.
  #pragma unroll
  for (int i = 0; i < 16; ++i) {
    u32 pk = (fbits(st[i >> 1][(i & 1) * 2]) >> 16) |
             (fbits(st[i >> 1][(i & 1) * 2 + 1]) & 0xFFFF0000u);
    Sp[i * 64 + l] = asf(pk);
  }

  // ---- Phase C: Z^T-tiles = Uhat^T . H (swapped operands) ---------------
  bf16x8 Hf[4];
  #pragma unroll
  for (int Nt = 0; Nt < 4; ++Nt) {       // n = b = (l&15)+16Nt, k = f
    u32x4 hw;
    #pragma unroll
    for (int i = 0; i < 4; ++i)
      hw[i] = fbits(Sp[(4 * (l >> 4) + i) * 64 + (l & 15) + 16 * Nt]);
    Hf[Nt] = asbf(hw);
  }

  float* zt = out_z + (size_t)tile * 64 * NF_D;
  #pragma unroll
  for (int Ntb = 0; Ntb < 4; ++Ntb) {    // b tile
    #pragma unroll
    for (int Mtd = 0; Mtd < 4; ++Mtd) {  // d tile (row-quads of D)
      f32x4v zz = {0.f, 0.f, 0.f, 0.f};
      zz = MFMA(Uf[Mtd], Hf[Ntb], zz, 0, 0, 0);
      int b = (l & 15) + 16 * Ntb;
      int d0 = 16 * Mtd + 4 * (l >> 4);
      f4 xr = *(const f4*)(xt + b * NF_D + d0);   // L2/L3-hot re-read
      f4 zv = {zz[0] + xr.x, zz[1] + xr.y, zz[2] + xr.z, zz[3] + xr.w};
      *(f4*)(zt + b * NF_D + d0) = zv;            // one f4 store per MFMA
    }
  }
  out_ld[(size_t)tile * 64 + l] =
      __builtin_amdgcn_logf(fabsf(ldp)) * 0.6931471805599453f;
}

extern "C" void kernel_launch(void* const* d_in, const int* in_sizes, int n_in,
                              void* d_out, int out_size, void* d_ws, size_t ws_size,
                              hipStream_t stream) {
  const float* x    = (const float*)d_in[0];
  const float* us   = (const float*)d_in[1];
  const float* ws_p = (const float*)d_in[2];
  const float* bs   = (const float*)d_in[3];
  const int B = in_sizes[0] / NF_D;

  u32* wsbuf = (u32*)d_ws;       // WS_TOT u32 ~ 16.5 KB
  float* out = (float*)d_out;    // z [B*64] then sum_log_det [B]

  nf_precompute<<<1, 256, 0, stream>>>(us, ws_p, wsbuf);
  const int ntiles = B / 64;     // 8192 one-wave blocks
  nf_main<<<ntiles, 64, 0, stream>>>(x, bs, wsbuf, out,
                                     out + (size_t)B * NF_D, B);
}

// Round 19
// 76.846 us; speedup vs baseline: 1.1714x; 1.1714x over previous
//
#include <hip/hip_runtime.h>
#include <math.h>

// Planar normalizing flow, B=524288 rows, D=64, F=32 -- MFMA formulation v8.
// Base = r14 (81us, verified). Two changes, NO inline asm (r18's NaN came
// from the hand-written v_cvt_pk_bf16_f32 asm -- the only semantic delta):
//  1. G/wuh/bs copied to LDS once per block; phase-B G-dot reads are
//     uniform-address ds_read_b128 (broadcast, VGPR-dest, pipelinable)
//     instead of s_loads capped by the ~112-SGPR in-flight ceiling.
//  2. Single-pass X: S = (Whi+Wlo) . rnd_bf16(X), with SOFTWARE RTNE
//     (bfrnd -- same integer-op helper that has rounded U-frags since
//     r12). MFMA 48->32, X-prep VALU ~= r14's hi/lo split cost.
// h-pack stays r14's truncation pack. Phase C unchanged (r14 epilogue).

#define NF_D 64
#define NF_F 32

typedef float f4 __attribute__((ext_vector_type(4)));
typedef float f32x4v __attribute__((ext_vector_type(4)));
typedef unsigned int u32;
typedef u32 u32x4 __attribute__((ext_vector_type(4)));
typedef short bf16x8 __attribute__((ext_vector_type(8)));

// wsbuf layout in 4-byte units:
#define WS_WF   0       // u32[8][64][4]  W A-frags, lin=(Mt*2+Kt)*2+p
#define WS_UF   2048    // u32[4][64][4]  Uhat B-frags (Nt)
#define WS_GT   3072    // float[32][32]  G[f][g]=u_hat_g.w_f (g<f else 0)
#define WS_WUH  4096    // float[32]      w_f.uhat_f
#define WS_TOT  4128

__device__ __forceinline__ u32 fbits(float x){ union{float f;u32 u;} c; c.f=x; return c.u; }
__device__ __forceinline__ float asf(u32 u){ union{u32 u;float f;} c; c.u=u; return c.f; }
__device__ __forceinline__ u32 bfrnd(float x){ u32 b=fbits(x); return (b + 0x7FFFu + ((b>>16)&1u)) >> 16; }
__device__ __forceinline__ bf16x8 asbf(u32x4 v){ union{u32x4 u; bf16x8 b;} c; c.u=v; return c.b; }

// --- precompute: uhat, wuh, G, W/U fragment buffers ----------------------
__global__ void nf_precompute(const float* __restrict__ us,
                              const float* __restrict__ ws,
                              u32* __restrict__ wsb) {
  __shared__ float s_u[NF_F][NF_D];
  float* wsf = (float*)wsb;
  int t = threadIdx.x;
  if (t < NF_F) {
    const float* u = us + t * NF_D;
    const float* w = ws + t * NF_D;
    float wu = 0.f, n2 = 0.f;
    for (int d = 0; d < NF_D; ++d) {
      wu = fmaf(u[d], w[d], wu);
      n2 = fmaf(w[d], w[d], n2);
    }
    float sp = fmaxf(wu, 0.f) + log1pf(expf(-fabsf(wu)));  // softplus
    float coef = (sp - 1.f - wu) / sqrtf(n2);
    for (int d = 0; d < NF_D; ++d)
      s_u[t][d] = fmaf(coef, w[d], u[d]);                  // uhat
    wsf[WS_WUH + t] = fmaf(coef, n2, wu);                  // w_t.uhat_t
  }
  __syncthreads();
  // W A-frags: lane l holds W[fm=16Mt+(l&15)][k=32Kt+8*(l>>4)+j], j=0..7
  // p=0: bf16-trunc(hi); p=1: bf16-trunc(w - hi)
  for (int idx = t; idx < 8 * 64; idx += 256) {
    int lin = idx >> 6, l = idx & 63;
    int Mt = lin >> 2, Kt = (lin >> 1) & 1, p = lin & 1;
    int fm = 16 * Mt + (l & 15);
    int kb = 32 * Kt + 8 * (l >> 4);
    for (int i = 0; i < 4; ++i) {
      u32 pr[2];
      for (int e = 0; e < 2; ++e) {
        float w = ws[fm * NF_D + kb + 2 * i + e];
        u32 hb = fbits(w) & 0xFFFF0000u;
        pr[e] = (p == 0) ? (hb >> 16) : (fbits(w - asf(hb)) >> 16);
      }
      wsb[WS_WF + (lin * 64 + l) * 4 + i] = pr[0] | (pr[1] << 16);
    }
  }
  // U frags: lane l holds Uhat[f=8*(l>>4)+j][d=16Nt+(l&15)], rounded bf16
  for (int idx = t; idx < 4 * 64; idx += 256) {
    int l = idx & 63;
    int d = 16 * (idx >> 6) + (l & 15);
    int fb = 8 * (l >> 4);
    for (int i = 0; i < 4; ++i) {
      u32 r0 = bfrnd(s_u[fb + 2 * i][d]);
      u32 r1 = bfrnd(s_u[fb + 2 * i + 1][d]);
      wsb[WS_UF + idx * 4 + i] = r0 | (r1 << 16);
    }
  }
  // G[f][g] = u_hat_g . w_f for g<f, else 0
  for (int i = t; i < NF_F * NF_F; i += 256) {
    int f = i >> 5, g = i & 31;
    float s = 0.f;
    if (g < f) {
      const float* w = ws + f * NF_D;
      for (int d = 0; d < NF_D; ++d) s = fmaf(s_u[g][d], w[d], s);
    }
    wsf[WS_GT + i] = s;
  }
}

// tanh(x) = 1 - 2/(e^{2x}+1); hardware exp2/rcp; saturates to +-1.
__device__ __forceinline__ float fast_tanh(float x) {
  float e = __builtin_amdgcn_exp2f(x * 2.885390081777927f); // 2*log2(e)
  return 1.f - 2.f * __builtin_amdgcn_rcpf(e + 1.f);
}

#define MFMA __builtin_amdgcn_mfma_f32_16x16x32_bf16

// --- main: one 64-row tile per wave --------------------------------------
__global__ __launch_bounds__(256) void nf_main(
    const float* __restrict__ x,
    const float* __restrict__ bs,
    const u32* __restrict__ wsb,
    float* __restrict__ out_z,
    float* __restrict__ out_ld,
    int B) {
  // Per-wave scratch: S[b][f] stride 33 (phase A->B); words [0,1024)
  // reused for packed-h (phase B->C). Same-wave program-order reuse only.
  __shared__ float S[4][64 * 33];
  // Block-shared params: G[32][32] | wuh[32] | bs[32] (one copy, 4.25KB)
  __shared__ float Gl[NF_F * NF_F + 2 * NF_F];
  const float* wsf = (const float*)wsb;

  // stage params to LDS (once per block; only sync point in the kernel)
  for (int i = threadIdx.x; i < NF_F * NF_F; i += 256)
    Gl[i] = wsf[WS_GT + i];
  if (threadIdx.x < NF_F) {
    Gl[NF_F * NF_F + threadIdx.x] = wsf[WS_WUH + threadIdx.x];
    Gl[NF_F * NF_F + NF_F + threadIdx.x] = bs[threadIdx.x];
  }
  __syncthreads();

  int wave = threadIdx.x >> 6;
  int l = threadIdx.x & 63;
  int ntiles = B / 64;
  int tile = blockIdx.x * 4 + wave;
  if (tile >= ntiles) tile = ntiles - 1;   // safety clamp (grid is exact)
  float* Sw = S[wave];

  // persistent param fragments (once per wave)
  bf16x8 Wf[2][2][2], Uf[4];
  #pragma unroll
  for (int q = 0; q < 8; ++q)
    Wf[q >> 2][(q >> 1) & 1][q & 1] =
        asbf(*(const u32x4*)(wsb + WS_WF + (q * 64 + l) * 4));
  #pragma unroll
  for (int Nt = 0; Nt < 4; ++Nt)
    Uf[Nt] = asbf(*(const u32x4*)(wsb + WS_UF + (Nt * 64 + l) * 4));

  const float* xt = x + (size_t)tile * 64 * NF_D;

  // ---- Phase A: S = (Whi+Wlo) . rnd_bf16(X)^T (single X pass) -----------
  #pragma unroll
  for (int Nt = 0; Nt < 4; ++Nt) {
    bf16x8 Xr[2];
    #pragma unroll
    for (int Kt = 0; Kt < 2; ++Kt) {
      const f4* xp = (const f4*)(xt + ((l & 15) + 16 * Nt) * NF_D +
                                 32 * Kt + 8 * (l >> 4));
      f4 xa = xp[0], xb = xp[1];
      u32x4 pw;
      pw[0] = bfrnd(xa.x) | (bfrnd(xa.y) << 16);   // software RTNE pack
      pw[1] = bfrnd(xa.z) | (bfrnd(xa.w) << 16);
      pw[2] = bfrnd(xb.x) | (bfrnd(xb.y) << 16);
      pw[3] = bfrnd(xb.z) | (bfrnd(xb.w) << 16);
      Xr[Kt] = asbf(pw);
    }
    #pragma unroll
    for (int Mt = 0; Mt < 2; ++Mt) {
      f32x4v a = {0.f, 0.f, 0.f, 0.f};
      #pragma unroll
      for (int Kt = 0; Kt < 2; ++Kt) {
        a = MFMA(Wf[Mt][Kt][0], Xr[Kt], a, 0, 0, 0);   // W-hi pass
        a = MFMA(Wf[Mt][Kt][1], Xr[Kt], a, 0, 0, 0);   // W-lo pass
      }
      // scatter S: C/D layout col=lane&15 (b in Ntile), row=4*(l>>4)+r
      #pragma unroll
      for (int r = 0; r < 4; ++r)
        Sw[((l & 15) + 16 * Nt) * 33 + 16 * Mt + 4 * (l >> 4) + r] = a[r];
    }
  }

  // ---- Phase B: per-lane row recurrence (lane = row b), G from LDS ------
  const float* gt = Gl;
  const float* wuhp = Gl + NF_F * NF_F;
  const float* bsl = Gl + NF_F * NF_F + NF_F;
  f4 hq[8];
  #pragma unroll
  for (int q = 0; q < 8; ++q) hq[q] = (f4)(0.f);   // zero: G pads are 0
  float ldp = 1.f;
  #pragma unroll
  for (int f = 0; f < NF_F; ++f) {
    const f4* g4 = (const f4*)(gt + f * 32);       // uniform ds_read_b128
    f4 a = (f4)(0.f);
    #pragma unroll
    for (int q = 0; q < (f + 3) / 4; ++q)
      a += g4[q] * hq[q];                  // chain f/4; pads hit G zeros
    float s = Sw[l * 33 + f] + bsl[f] + ((a.x + a.y) + (a.z + a.w));
    float hf = fast_tanh(s);
    ldp *= fmaf(fmaf(-hf, hf, 1.f), wuhp[f], 1.f);
    hq[f >> 2][f & 3] = hf;
  }
  // pack h -> bf16 pairs into S words [0,1024): Hw[i][b], b = lane.
  #pragma unroll
  for (int i = 0; i < 16; ++i) {
    u32 pk = (fbits(hq[i >> 1][(i & 1) * 2]) >> 16) |
             (fbits(hq[i >> 1][(i & 1) * 2 + 1]) & 0xFFFF0000u);
    Sw[i * 64 + l] = asf(pk);
  }

  // ---- Phase C: Z = X + Uhat^T h, direct epilogue (r14-style) -----------
  bf16x8 Hf[4];
  #pragma unroll
  for (int Mt = 0; Mt < 4; ++Mt) {
    u32x4 hw;
    #pragma unroll
    for (int i = 0; i < 4; ++i)
      hw[i] = fbits(Sw[(4 * (l >> 4) + i) * 64 + (l & 15) + 16 * Mt]);
    Hf[Mt] = asbf(hw);
  }

  float* zt = out_z + (size_t)tile * 64 * NF_D;
  #pragma unroll
  for (int Mt = 0; Mt < 4; ++Mt) {
    #pragma unroll
    for (int Nt = 0; Nt < 4; ++Nt) {
      f32x4v zz = {0.f, 0.f, 0.f, 0.f};
      zz = MFMA(Hf[Mt], Uf[Nt], zz, 0, 0, 0);
      #pragma unroll
      for (int r = 0; r < 4; ++r) {
        int brow = 16 * Mt + 4 * (l >> 4) + r;
        int d = (l & 15) + 16 * Nt;
        zt[brow * NF_D + d] = zz[r] + xt[brow * NF_D + d];  // x: L1/L2-hot
      }
    }
  }
  out_ld[(size_t)tile * 64 + l] =
      __builtin_amdgcn_logf(fabsf(ldp)) * 0.6931471805599453f;
}

extern "C" void kernel_launch(void* const* d_in, const int* in_sizes, int n_in,
                              void* d_out, int out_size, void* d_ws, size_t ws_size,
                              hipStream_t stream) {
  const float* x    = (const float*)d_in[0];
  const float* us   = (const float*)d_in[1];
  const float* ws_p = (const float*)d_in[2];
  const float* bs   = (const float*)d_in[3];
  const int B = in_sizes[0] / NF_D;

  u32* wsbuf = (u32*)d_ws;       // WS_TOT u32 ~ 16.5 KB
  float* out = (float*)d_out;    // z [B*64] then sum_log_det [B]

  nf_precompute<<<1, 256, 0, stream>>>(us, ws_p, wsbuf);
  const int ntiles = B / 64;
  const int grid = (ntiles + 3) / 4;
  nf_main<<<grid, 256, 0, stream>>>(x, bs, wsbuf, out,
                                    out + (size_t)B * NF_D, B);
}